// Round 1
// baseline (664.185 us; speedup 1.0000x reference)
//
#include <hip/hip_runtime.h>

// GAT (2-layer) + global mean pool + linear, MI355X.
// Strategy: build CSR-by-dst on device (hist -> scan -> scatter), then
// gather-based per-dst softmax aggregation (one 64-lane wave per dst node,
// lane = feature). No float atomics anywhere.

constexpr int FH = 64;        // hidden/out feature width (both layers)
constexpr float NEG_SLOPE = 0.2f;
constexpr float EPS = 1e-16f;

// ---------------- CSR build ----------------

__global__ void hist_kernel(const int* __restrict__ ei, int* __restrict__ deg,
                            int E, int N) {
  int e = blockIdx.x * blockDim.x + threadIdx.x;
  if (e >= E + N) return;
  int dst = (e < E) ? ei[E + e] : (e - E);   // self-loops appended
  atomicAdd(&deg[dst], 1);
}

// single-block exclusive scan (n up to ~64k is fine: 1024 threads, chunked)
__global__ void scan_kernel(const int* __restrict__ deg, int* __restrict__ rowptr,
                            int n) {
  __shared__ int buf[1024];
  __shared__ int carry;
  int t = threadIdx.x;
  if (t == 0) carry = 0;
  __syncthreads();
  for (int base = 0; base < n; base += 1024) {
    int i = base + t;
    int v = (i < n) ? deg[i] : 0;
    buf[t] = v;
    __syncthreads();
    for (int off = 1; off < 1024; off <<= 1) {
      int add = (t >= off) ? buf[t - off] : 0;
      __syncthreads();
      buf[t] += add;
      __syncthreads();
    }
    if (i < n) rowptr[i] = carry + buf[t] - v;   // exclusive
    __syncthreads();
    if (t == 0) carry += buf[1023];
    __syncthreads();
  }
  if (t == 0) rowptr[n] = carry;
}

__global__ void scatter_kernel(const int* __restrict__ ei, int* __restrict__ cursor,
                               int* __restrict__ eidx, int E, int N) {
  int e = blockIdx.x * blockDim.x + threadIdx.x;
  if (e >= E + N) return;
  int src, dst;
  if (e < E) { src = ei[e]; dst = ei[E + e]; }
  else       { src = dst = e - E; }
  int pos = atomicAdd(&cursor[dst], 1);
  eidx[pos] = src;
}

// ---------------- h = x @ W, plus alpha_s/alpha_d dot products ----------------
// Block = 256 threads = 4 waves; each wave owns one row at a time, lane = out col.
// W staged in LDS; x row read as float4 (wave-uniform broadcast loads).

template <int FIN>
__global__ void gemm_alpha_kernel(const float* __restrict__ x,
                                  const float* __restrict__ W,
                                  const float* __restrict__ avs,
                                  const float* __restrict__ avd,
                                  float* __restrict__ h,
                                  float* __restrict__ as,
                                  float* __restrict__ ad, int n) {
  __shared__ float Wl[FIN][FH];
  for (int i = threadIdx.x; i < FIN * FH; i += blockDim.x)
    Wl[i / FH][i % FH] = W[i];
  __syncthreads();

  int wave = threadIdx.x >> 6;
  int lane = threadIdx.x & 63;
  float asc = avs[lane];
  float adc = avd[lane];
  int nw = gridDim.x * 4;
  for (int row = blockIdx.x * 4 + wave; row < n; row += nw) {
    const float* xr = x + (size_t)row * FIN;
    float acc = 0.f;
#pragma unroll
    for (int k = 0; k < FIN; k += 4) {
      float4 xv = *reinterpret_cast<const float4*>(xr + k);
      acc += xv.x * Wl[k + 0][lane];
      acc += xv.y * Wl[k + 1][lane];
      acc += xv.z * Wl[k + 2][lane];
      acc += xv.w * Wl[k + 3][lane];
    }
    h[(size_t)row * FH + lane] = acc;
    float s = acc * asc, d = acc * adc;
#pragma unroll
    for (int off = 32; off; off >>= 1) {
      s += __shfl_xor(s, off);
      d += __shfl_xor(d, off);
    }
    if (lane == 0) { as[row] = s; ad[row] = d; }
  }
}

// ---------------- per-dst softmax aggregation (gather) ----------------
// One wave per dst. Pass 1: lanes stride edges, reduce max(logit).
// Pass 2: serial edge loop; lane c accumulates sum_j e_j * h[src_j][c];
// denom accumulated redundantly in every lane. Normalize + bias (+relu) once.

__global__ void agg_kernel(const int* __restrict__ rowptr,
                           const int* __restrict__ eidx,
                           const float* __restrict__ h,
                           const float* __restrict__ as,
                           const float* __restrict__ ad,
                           const float* __restrict__ b,
                           float* __restrict__ out, int n, int doRelu) {
  int wave = (blockIdx.x * blockDim.x + threadIdx.x) >> 6;
  int lane = threadIdx.x & 63;
  int nwaves = (gridDim.x * blockDim.x) >> 6;
  float bc = b[lane];
  for (int dst = wave; dst < n; dst += nwaves) {
    int lo = rowptr[dst], hi = rowptr[dst + 1];
    float adv = ad[dst];
    // pass 1: max logit
    float m = -1e30f;
    for (int j = lo + lane; j < hi; j += 64) {
      float t = as[eidx[j]] + adv;
      t = (t > 0.f) ? t : NEG_SLOPE * t;
      m = fmaxf(m, t);
    }
#pragma unroll
    for (int off = 32; off; off >>= 1) m = fmaxf(m, __shfl_xor(m, off));
    // pass 2: weighted accumulate
    float acc = 0.f, den = 0.f;
    for (int j = lo; j < hi; ++j) {
      int s = eidx[j];                        // wave-uniform
      float t = as[s] + adv;                  // broadcast load
      t = (t > 0.f) ? t : NEG_SLOPE * t;
      float w = expf(t - m);
      den += w;
      acc += w * h[(size_t)s * FH + lane];    // coalesced 256B gather
    }
    float o = acc / (den + EPS) + bc;
    if (doRelu) o = fmaxf(o, 0.f);
    out[(size_t)dst * FH + lane] = o;
  }
}

// ---------------- mean-pool per graph + final linear ----------------
// One wave per graph; batch is sorted -> binary-search the node range.

__global__ void pool_kernel(const int* __restrict__ batch,
                            const float* __restrict__ h,
                            const float* __restrict__ Wlin,
                            const float* __restrict__ blin,
                            float* __restrict__ outp, int n, int ncls) {
  int g = blockIdx.x;
  __shared__ int sh[2];
  if (threadIdx.x == 0) {
    int lo = 0, hi = n;
    while (lo < hi) { int mid = (lo + hi) >> 1; if (batch[mid] < g) lo = mid + 1; else hi = mid; }
    sh[0] = lo;
    hi = n;
    while (lo < hi) { int mid = (lo + hi) >> 1; if (batch[mid] <= g) lo = mid + 1; else hi = mid; }
    sh[1] = lo;
  }
  __syncthreads();
  int lo = sh[0], hi = sh[1];
  int lane = threadIdx.x;  // blockDim = 64
  float acc = 0.f;
  for (int i = lo; i < hi; ++i) acc += h[(size_t)i * FH + lane];
  float pooled = acc / fmaxf((float)(hi - lo), 1.f);
  for (int k = 0; k < ncls; ++k) {
    float v = pooled * Wlin[lane * ncls + k];
#pragma unroll
    for (int off = 32; off; off >>= 1) v += __shfl_xor(v, off);
    if (lane == 0) outp[g * ncls + k] = v + blin[k];
  }
}

// ---------------- launch ----------------

extern "C" void kernel_launch(void* const* d_in, const int* in_sizes, int n_in,
                              void* d_out, int out_size, void* d_ws, size_t ws_size,
                              hipStream_t stream) {
  const float* x    = (const float*)d_in[0];
  const int*   ei   = (const int*)d_in[1];
  const int*   batch= (const int*)d_in[2];
  const float* W1   = (const float*)d_in[3];
  const float* as1  = (const float*)d_in[4];
  const float* ad1  = (const float*)d_in[5];
  const float* b1   = (const float*)d_in[6];
  const float* W2   = (const float*)d_in[7];
  const float* as2  = (const float*)d_in[8];
  const float* ad2  = (const float*)d_in[9];
  const float* b2   = (const float*)d_in[10];
  const float* Wlin = (const float*)d_in[11];
  const float* blin = (const float*)d_in[12];
  float* outp = (float*)d_out;

  const int N  = in_sizes[2];        // 50000 (batch length)
  const int E  = in_sizes[1] / 2;    // 800000
  const int ET = E + N;              // + self loops
  const int NCLS = 10;
  const int NG = out_size / NCLS;    // 512

  // workspace layout (~30 MB)
  char* p = (char*)d_ws;
  auto alloc = [&](size_t bytes) {
    char* r = p;
    p += (bytes + 255) & ~(size_t)255;
    return r;
  };
  float* hA     = (float*)alloc((size_t)N * FH * 4);
  float* hB     = (float*)alloc((size_t)N * FH * 4);
  float* asb    = (float*)alloc((size_t)N * 4);
  float* adb    = (float*)alloc((size_t)N * 4);
  int*   deg    = (int*)alloc((size_t)N * 4);
  int*   rowptr = (int*)alloc((size_t)(N + 1) * 4);
  int*   cursor = (int*)alloc((size_t)N * 4);
  int*   eidx   = (int*)alloc((size_t)ET * 4);
  (void)ws_size; (void)n_in;

  const int TB = 256;

  // CSR by dst
  hipMemsetAsync(deg, 0, (size_t)N * 4, stream);
  hist_kernel<<<(ET + TB - 1) / TB, TB, 0, stream>>>(ei, deg, E, N);
  scan_kernel<<<1, 1024, 0, stream>>>(deg, rowptr, N);
  hipMemcpyAsync(cursor, rowptr, (size_t)N * 4, hipMemcpyDeviceToDevice, stream);
  scatter_kernel<<<(ET + TB - 1) / TB, TB, 0, stream>>>(ei, cursor, eidx, E, N);

  int aggBlocks = (N + 3) / 4;       // 4 waves/block, 1 wave/dst

  // layer 1: h1 = x@W1 ; out1 = relu(agg + b1)
  gemm_alpha_kernel<128><<<2048, TB, 0, stream>>>(x, W1, as1, ad1, hA, asb, adb, N);
  agg_kernel<<<aggBlocks, TB, 0, stream>>>(rowptr, eidx, hA, asb, adb, b1, hB, N, 1);

  // layer 2: h2 = out1@W2 ; out2 = agg + b2
  gemm_alpha_kernel<64><<<2048, TB, 0, stream>>>(hB, W2, as2, ad2, hA, asb, adb, N);
  agg_kernel<<<aggBlocks, TB, 0, stream>>>(rowptr, eidx, hA, asb, adb, b2, hB, N, 0);

  // mean pool per graph + linear
  pool_kernel<<<NG, 64, 0, stream>>>(batch, hB, Wlin, blin, outp, N, NCLS);
}